// Round 1
// baseline (400.920 us; speedup 1.0000x reference)
//
#include <hip/hip_runtime.h>
#include <hip/hip_bf16.h>
#include <cstdint>
#include <cstddef>

typedef __attribute__((ext_vector_type(4))) float f32x4;
typedef __attribute__((ext_vector_type(8))) short bf16x8;
typedef unsigned int u32;
typedef unsigned short u16;

// ---------- helpers ----------

__device__ __forceinline__ u16 f2bf(float x) {
  u32 u = __builtin_bit_cast(u32, x);
  u += 0x7fffu + ((u >> 16) & 1u);   // round-to-nearest-even
  return (u16)(u >> 16);
}

// async global->LDS, 16B per lane. Dest must be wave-linear (base + lane*16).
__device__ __forceinline__ void gl_lds16(const void* g, void* l) {
  __builtin_amdgcn_global_load_lds(
      (const __attribute__((address_space(1))) u32*)(uintptr_t)g,
      (__attribute__((address_space(3))) u32*)(u32)(uintptr_t)l,
      16, 0, 0);
}

#define MFMA16(a, b, c) __builtin_amdgcn_mfma_f32_16x16x32_bf16((a), (b), (c), 0, 0, 0)

// ---------- cast fp32 -> bf16 (vectorized x4) ----------

__global__ void cast_f32_bf16_v4(const float* __restrict__ src, u16* __restrict__ dst, int n4) {
  int i = blockIdx.x * 256 + threadIdx.x;
  if (i >= n4) return;
  const float4 v = reinterpret_cast<const float4*>(src)[i];
  union { u16 s[4]; uint2 u; } o;
  o.s[0] = f2bf(v.x); o.s[1] = f2bf(v.y); o.s[2] = f2bf(v.z); o.s[3] = f2bf(v.w);
  reinterpret_cast<uint2*>(dst)[i] = o.u;
}

// ---------- rope cos/sin table: [S][32] ----------

__global__ void rope_table_k(const int* __restrict__ pos, float* __restrict__ cosT,
                             float* __restrict__ sinT) {
  int idx = blockIdx.x * 256 + threadIdx.x;   // S*32 = 65536
  int s = idx >> 5, i = idx & 31;
  float inv = powf(10000.0f, -(float)i * (1.0f / 32.0f));
  float ang = (float)pos[s] * inv;
  cosT[idx] = cosf(ang);
  sinT[idx] = sinf(ang);
}

// ---------- rope apply: tmp fp32 [b,s,h*64+dk] -> bf16 [b,h,s,dk], scaled ----------

__global__ void rope_apply_k(const float* __restrict__ src, const float* __restrict__ cosT,
                             const float* __restrict__ sinT, u16* __restrict__ dst, float scale) {
  int p = blockIdx.x * 256 + threadIdx.x;     // 2^22 pairs
  int i = p & 31, h = (p >> 5) & 15, s = (p >> 9) & 2047, b = p >> 20;
  const float2 v = *reinterpret_cast<const float2*>(
      src + ((size_t)(b * 2048 + s) << 10) + h * 64 + 2 * i);
  float c = cosT[(s << 5) + i], sn = sinT[(s << 5) + i];
  float e = (v.x * c - v.y * sn) * scale;
  float o = (v.x * sn + v.y * c) * scale;
  u32 packed = (u32)f2bf(e) | ((u32)f2bf(o) << 16);
  *reinterpret_cast<u32*>(dst + ((size_t)((b * 16 + h) * 2048 + s) << 6) + 2 * i) = packed;
}

// ---------- V transpose: tmp fp32 [b,s,h*64+dk] -> bf16 Vt [b,h,dk,s] ----------

__global__ void transpose_v_k(const float* __restrict__ src, u16* __restrict__ dst) {
  __shared__ float tile[64][65];
  int s0 = blockIdx.x * 64, bh = blockIdx.y;
  int b = bh >> 4, h = bh & 15;
  int tid = threadIdx.x;
  int c = tid & 63, r0 = tid >> 6;
  const float* sp = src + ((size_t)(b * 2048 + s0) << 10) + h * 64;
#pragma unroll
  for (int rr = 0; rr < 16; ++rr) {
    int r = rr * 4 + r0;
    tile[r][c] = sp[((size_t)r << 10) + c];
  }
  __syncthreads();
  u16* dp = dst + ((size_t)bh << 17) + s0;    // bh*64*2048
#pragma unroll
  for (int rr = 0; rr < 16; ++rr) {
    int dk = rr * 4 + r0;
    dp[((size_t)dk << 11) + c] = f2bf(tile[c][dk]);
  }
}

// ---------- GEMM: C(MxN fp32) = A(MxK bf16 rm) * B^T (B: NxK bf16 rm) ----------
// 128x128 tile, BK=32, 256 threads (4 waves 2x2), global_load_lds staging with
// pre-swizzled source (slot ^ ((row>>1)&3)) so ds_read_b128 frags are ~2-way.

__global__ __launch_bounds__(256, 2)
void gemm_bt(const u16* __restrict__ A, const u16* __restrict__ B,
             float* __restrict__ C, int M, int N, int K) {
  __shared__ u16 a_lds[2][128 * 32];
  __shared__ u16 b_lds[2][128 * 32];
  const int tid = threadIdx.x;
  const int l = tid & 63;
  const int w = tid >> 6;
  const int wm = w >> 1, wn = w & 1;
  const int bm = blockIdx.y, bn = blockIdx.x;

  const u16* Ab = A + (size_t)bm * 128 * K;
  const u16* Bb = B + (size_t)bn * 128 * K;

  auto stage = [&](int bq, int k0) {
#pragma unroll
    for (int half = 0; half < 2; ++half) {
      int t = half * 256 + tid;
      int row = t >> 2, slot = t & 3;
      int sp = slot ^ ((row >> 1) & 3);
      gl_lds16(Ab + (size_t)row * K + k0 + sp * 8, &a_lds[bq][t * 8]);
      gl_lds16(Bb + (size_t)row * K + k0 + sp * 8, &b_lds[bq][t * 8]);
    }
  };

  const f32x4 fz = {0.f, 0.f, 0.f, 0.f};
  f32x4 acc[4][4];
#pragma unroll
  for (int mi = 0; mi < 4; ++mi)
#pragma unroll
    for (int ni = 0; ni < 4; ++ni) acc[mi][ni] = fz;

  const int nk = K >> 5;
  stage(0, 0);
  int buf = 0;
  for (int kt = 0; kt < nk; ++kt) {
    __syncthreads();                       // staging for buf complete; prev readers done
    if (kt + 1 < nk) stage(buf ^ 1, (kt + 1) * 32);
    bf16x8 af[4], bf[4];
#pragma unroll
    for (int mi = 0; mi < 4; ++mi) {
      int row = wm * 64 + mi * 16 + (l & 15);
      int sp = (l >> 4) ^ ((row >> 1) & 3);
      af[mi] = *(const bf16x8*)&a_lds[buf][row * 32 + sp * 8];
    }
#pragma unroll
    for (int ni = 0; ni < 4; ++ni) {
      int row = wn * 64 + ni * 16 + (l & 15);
      int sp = (l >> 4) ^ ((row >> 1) & 3);
      bf[ni] = *(const bf16x8*)&b_lds[buf][row * 32 + sp * 8];
    }
#pragma unroll
    for (int mi = 0; mi < 4; ++mi)
#pragma unroll
      for (int ni = 0; ni < 4; ++ni)
        acc[mi][ni] = MFMA16(af[mi], bf[ni], acc[mi][ni]);
    buf ^= 1;
  }

#pragma unroll
  for (int mi = 0; mi < 4; ++mi) {
    int rbase = bm * 128 + wm * 64 + mi * 16 + ((l >> 4) << 2);
#pragma unroll
    for (int ni = 0; ni < 4; ++ni) {
      int col = bn * 128 + wn * 64 + ni * 16 + (l & 15);
      f32x4 v = acc[mi][ni];
#pragma unroll
      for (int j = 0; j < 4; ++j)
        C[(size_t)(rbase + j) * N + col] = v[j];
    }
  }
}

// ---------- causal flash attention ----------
// Q/K: bf16 [b,h,s,64] (Q pre-scaled by 1/8), Vt: bf16 [b,h,64,s], O: bf16 [b,s,h*64+dk]
// grid (S/128, B*H), 256 thr = 4 waves x 32 q-rows; kv tiles 64, double-buffered.

__global__ __launch_bounds__(256, 2)
void attn_k(const u16* __restrict__ Q, const u16* __restrict__ K,
            const u16* __restrict__ V, u16* __restrict__ O) {
  const int S = 2048;
  __shared__ u16 q_lds[128 * 64];
  __shared__ u16 k_lds[2][64 * 64];
  __shared__ u16 v_lds[2][64 * 64];       // [dk][kv]
  __shared__ u16 p_lds[4][32 * 64];       // per-wave

  const int tid = threadIdx.x, l = tid & 63, w = tid >> 6;
  const int qblk = blockIdx.x, bh = blockIdx.y;
  const u16* Qb = Q + ((size_t)bh * S + qblk * 128) * 64;
  const u16* Kb = K + (size_t)bh * S * 64;
  const u16* Vb = V + (size_t)bh * 64 * S;

  // stage Q (128 rows x 128B), swizzled source
#pragma unroll
  for (int half = 0; half < 4; ++half) {
    int t = half * 256 + tid;
    int row = t >> 3, slot = t & 7;
    int sp = slot ^ (row & 7);
    gl_lds16(Qb + row * 64 + sp * 8, &q_lds[t * 8]);
  }

  auto stageKV = [&](int bq, int kv0) {
#pragma unroll
    for (int half = 0; half < 2; ++half) {
      int t = half * 256 + tid;
      int row = t >> 3, slot = t & 7;
      int sp = slot ^ (row & 7);
      gl_lds16(Kb + (size_t)(kv0 + row) * 64 + sp * 8, &k_lds[bq][t * 8]);
      gl_lds16(Vb + (size_t)row * S + kv0 + sp * 8, &v_lds[bq][t * 8]);
    }
  };

  const f32x4 fz = {0.f, 0.f, 0.f, 0.f};
  f32x4 oacc[2][4];
  float m_run[2][4], l_run[2][4];
#pragma unroll
  for (int mi = 0; mi < 2; ++mi)
#pragma unroll
    for (int j = 0; j < 4; ++j) { m_run[mi][j] = -1e30f; l_run[mi][j] = 0.f; }
#pragma unroll
  for (int mi = 0; mi < 2; ++mi)
#pragma unroll
    for (int ni = 0; ni < 4; ++ni) oacc[mi][ni] = fz;

  const int nkv = qblk * 2 + 2;
  stageKV(0, 0);
  int buf = 0;
  for (int kv = 0; kv < nkv; ++kv) {
    __syncthreads();                       // staging of buf done; prev readers done
    if (kv + 1 < nkv) stageKV(buf ^ 1, (kv + 1) * 64);

    // S = Q * K^T (per wave: 32 q-rows x 64 kv)
    f32x4 sacc[2][4];
#pragma unroll
    for (int mi = 0; mi < 2; ++mi)
#pragma unroll
      for (int ni = 0; ni < 4; ++ni) sacc[mi][ni] = fz;
#pragma unroll
    for (int ks = 0; ks < 2; ++ks) {
      bf16x8 aq[2];
#pragma unroll
      for (int mi = 0; mi < 2; ++mi) {
        int row = w * 32 + mi * 16 + (l & 15);
        int sp = (ks * 4 + (l >> 4)) ^ (row & 7);
        aq[mi] = *(const bf16x8*)&q_lds[row * 64 + sp * 8];
      }
#pragma unroll
      for (int ni = 0; ni < 4; ++ni) {
        int kr = ni * 16 + (l & 15);
        int sp = (ks * 4 + (l >> 4)) ^ (kr & 7);
        bf16x8 bk = *(const bf16x8*)&k_lds[buf][kr * 64 + sp * 8];
#pragma unroll
        for (int mi = 0; mi < 2; ++mi)
          sacc[mi][ni] = MFMA16(aq[mi], bk, sacc[mi][ni]);
      }
    }

    // causal mask + online softmax (wave-parallel row reduce over 16-lane groups)
    const int row_base = qblk * 128 + w * 32;
    const bool diag = (kv * 64 + 63) > row_base;   // wave-uniform
#pragma unroll
    for (int mi = 0; mi < 2; ++mi) {
#pragma unroll
      for (int j = 0; j < 4; ++j) {
        int row = row_base + mi * 16 + ((l >> 4) << 2) + j;
        if (diag) {
#pragma unroll
          for (int ni = 0; ni < 4; ++ni) {
            int col = kv * 64 + ni * 16 + (l & 15);
            if (col > row) sacc[mi][ni][j] = -1e30f;
          }
        }
        float mx = fmaxf(fmaxf(sacc[mi][0][j], sacc[mi][1][j]),
                         fmaxf(sacc[mi][2][j], sacc[mi][3][j]));
        mx = fmaxf(mx, __shfl_xor(mx, 1));
        mx = fmaxf(mx, __shfl_xor(mx, 2));
        mx = fmaxf(mx, __shfl_xor(mx, 4));
        mx = fmaxf(mx, __shfl_xor(mx, 8));
        float mnew = fmaxf(m_run[mi][j], mx);
        float alpha = __expf(m_run[mi][j] - mnew);
        float ps = 0.f;
#pragma unroll
        for (int ni = 0; ni < 4; ++ni) {
          float p = __expf(sacc[mi][ni][j] - mnew);
          sacc[mi][ni][j] = p;
          ps += p;
        }
        ps += __shfl_xor(ps, 1);
        ps += __shfl_xor(ps, 2);
        ps += __shfl_xor(ps, 4);
        ps += __shfl_xor(ps, 8);
        l_run[mi][j] = l_run[mi][j] * alpha + ps;
        m_run[mi][j] = mnew;
#pragma unroll
        for (int ni = 0; ni < 4; ++ni) oacc[mi][ni][j] *= alpha;
      }
    }

    // P -> per-wave LDS (bf16, swizzled rows of 128B)
#pragma unroll
    for (int mi = 0; mi < 2; ++mi)
#pragma unroll
      for (int ni = 0; ni < 4; ++ni) {
        int col = ni * 16 + (l & 15);
#pragma unroll
        for (int j = 0; j < 4; ++j) {
          int row = mi * 16 + ((l >> 4) << 2) + j;
          int sp = (col >> 3) ^ (row & 7);
          p_lds[w][row * 64 + sp * 8 + (col & 7)] = f2bf(sacc[mi][ni][j]);
        }
      }

    // O += P * V
#pragma unroll
    for (int ks = 0; ks < 2; ++ks) {
      bf16x8 ap[2];
#pragma unroll
      for (int mi = 0; mi < 2; ++mi) {
        int row = mi * 16 + (l & 15);
        int sp = (ks * 4 + (l >> 4)) ^ (row & 7);
        ap[mi] = *(const bf16x8*)&p_lds[w][row * 64 + sp * 8];
      }
#pragma unroll
      for (int ni = 0; ni < 4; ++ni) {
        int vr = ni * 16 + (l & 15);
        int sp = (ks * 4 + (l >> 4)) ^ (vr & 7);
        bf16x8 bv = *(const bf16x8*)&v_lds[buf][vr * 64 + sp * 8];
#pragma unroll
        for (int mi = 0; mi < 2; ++mi)
          oacc[mi][ni] = MFMA16(ap[mi], bv, oacc[mi][ni]);
      }
    }
    buf ^= 1;
  }

  // epilogue: O /= l, write bf16 [b, s, h*64+dk]
  const int b = bh >> 4, h = bh & 15;
#pragma unroll
  for (int mi = 0; mi < 2; ++mi)
#pragma unroll
    for (int j = 0; j < 4; ++j) {
      int srow = qblk * 128 + w * 32 + mi * 16 + ((l >> 4) << 2) + j;
      float inv = 1.f / l_run[mi][j];
#pragma unroll
      for (int ni = 0; ni < 4; ++ni) {
        int dk = ni * 16 + (l & 15);
        O[((size_t)(b * 2048 + srow) << 10) + h * 64 + dk] = f2bf(oacc[mi][ni][j] * inv);
      }
    }
}

// ---------- launch ----------

extern "C" void kernel_launch(void* const* d_in, const int* in_sizes, int n_in,
                              void* d_out, int out_size, void* d_ws, size_t ws_size,
                              hipStream_t stream) {
  (void)in_sizes; (void)n_in; (void)out_size; (void)ws_size;
  const float* x  = (const float*)d_in[0];
  const int* pos  = (const int*)d_in[1];
  const float* Wq = (const float*)d_in[2];
  const float* Wk = (const float*)d_in[3];
  const float* Wv = (const float*)d_in[4];
  const float* Wo = (const float*)d_in[5];
  float* out = (float*)d_out;

  const int S = 2048, D = 1024;
  const size_t M = (size_t)4 * S;          // 8192

  char* ws = (char*)d_ws;
  size_t off = 0;
  auto alloc = [&](size_t bytes) {
    void* p = ws + off;
    off += (bytes + 255) & ~(size_t)255;
    return p;
  };
  u16* xb   = (u16*)alloc(M * D * 2);
  u16* wqb  = (u16*)alloc((size_t)D * D * 2);
  u16* wkb  = (u16*)alloc((size_t)D * D * 2);
  u16* wvb  = (u16*)alloc((size_t)D * D * 2);
  u16* wob  = (u16*)alloc((size_t)D * D * 2);
  float* tmp = (float*)alloc(M * D * 4);
  u16* Qr   = (u16*)alloc(M * D * 2);
  u16* Kr   = (u16*)alloc(M * D * 2);
  u16* Vt   = (u16*)alloc(M * D * 2);
  u16* Ob   = (u16*)alloc(M * D * 2);
  float* cosT = (float*)alloc((size_t)S * 32 * 4);
  float* sinT = (float*)alloc((size_t)S * 32 * 4);

  const int nx4 = (int)(M * D / 4);        // 2M
  const int nw4 = D * D / 4;               // 256K
  cast_f32_bf16_v4<<<(nx4 + 255) / 256, 256, 0, stream>>>(x, xb, nx4);
  cast_f32_bf16_v4<<<(nw4 + 255) / 256, 256, 0, stream>>>(Wq, wqb, nw4);
  cast_f32_bf16_v4<<<(nw4 + 255) / 256, 256, 0, stream>>>(Wk, wkb, nw4);
  cast_f32_bf16_v4<<<(nw4 + 255) / 256, 256, 0, stream>>>(Wv, wvb, nw4);
  cast_f32_bf16_v4<<<(nw4 + 255) / 256, 256, 0, stream>>>(Wo, wob, nw4);
  rope_table_k<<<(S * 32) / 256, 256, 0, stream>>>(pos, cosT, sinT);

  dim3 ggrid(D / 128, (unsigned)(M / 128));   // (8, 64)
  const int nrope = (int)(M * D / 2 / 256);   // 16384 blocks of 256 pairs

  gemm_bt<<<ggrid, 256, 0, stream>>>(xb, wqb, tmp, (int)M, D, D);
  rope_apply_k<<<nrope, 256, 0, stream>>>(tmp, cosT, sinT, Qr, 0.125f);  // Q pre-scaled 1/sqrt(64)
  gemm_bt<<<ggrid, 256, 0, stream>>>(xb, wkb, tmp, (int)M, D, D);
  rope_apply_k<<<nrope, 256, 0, stream>>>(tmp, cosT, sinT, Kr, 1.0f);
  gemm_bt<<<ggrid, 256, 0, stream>>>(xb, wvb, tmp, (int)M, D, D);
  transpose_v_k<<<dim3(S / 64, 64), 256, 0, stream>>>(tmp, Vt);
  attn_k<<<dim3(S / 128, 64), 256, 0, stream>>>(Qr, Kr, Vt, Ob);
  gemm_bt<<<ggrid, 256, 0, stream>>>(Ob, wob, out, (int)M, D, D);
}

// Round 3
// 250.836 us; speedup vs baseline: 1.5983x; 1.5983x over previous
//
#include <hip/hip_runtime.h>
#include <hip/hip_bf16.h>
#include <cstdint>
#include <cstddef>

typedef __attribute__((ext_vector_type(4))) float f32x4;
typedef __attribute__((ext_vector_type(8))) short bf16x8;
typedef unsigned int u32;
typedef unsigned short u16;

// ---------- helpers ----------

__device__ __forceinline__ u16 f2bf(float x) {
  u32 u = __builtin_bit_cast(u32, x);
  u += 0x7fffu + ((u >> 16) & 1u);   // round-to-nearest-even
  return (u16)(u >> 16);
}

__device__ __forceinline__ u32 pack_bf16(float lo, float hi) {
  return (u32)f2bf(lo) | ((u32)f2bf(hi) << 16);
}

// async global->LDS, 16B per lane. Dest must be wave-linear (base + lane*16).
__device__ __forceinline__ void gl_lds16(const void* g, void* l) {
  __builtin_amdgcn_global_load_lds(
      (const __attribute__((address_space(1))) u32*)(uintptr_t)g,
      (__attribute__((address_space(3))) u32*)(u32)(uintptr_t)l,
      16, 0, 0);
}

#define MFMA16(a, b, c) __builtin_amdgcn_mfma_f32_16x16x32_bf16((a), (b), (c), 0, 0, 0)

// ---------- cast fp32 -> bf16 (vectorized x4) ----------

__global__ void cast_f32_bf16_v4(const float* __restrict__ src, u16* __restrict__ dst, int n4) {
  int i = blockIdx.x * 256 + threadIdx.x;
  if (i >= n4) return;
  const float4 v = reinterpret_cast<const float4*>(src)[i];
  union { u16 s[4]; uint2 u; } o;
  o.s[0] = f2bf(v.x); o.s[1] = f2bf(v.y); o.s[2] = f2bf(v.z); o.s[3] = f2bf(v.w);
  reinterpret_cast<uint2*>(dst)[i] = o.u;
}

// ---------- rope cos/sin table: [S][32] ----------

__global__ void rope_table_k(const int* __restrict__ pos, float* __restrict__ cosT,
                             float* __restrict__ sinT) {
  int idx = blockIdx.x * 256 + threadIdx.x;   // S*32 = 65536
  int s = idx >> 5, i = idx & 31;
  float inv = powf(10000.0f, -(float)i * (1.0f / 32.0f));
  float ang = (float)pos[s] * inv;
  cosT[idx] = cosf(ang);
  sinT[idx] = sinf(ang);
}

// ---------- rope apply: tmp fp32 [b,s,h*64+dk] -> bf16 [b,h,s,dk], scaled ----------

__global__ void rope_apply_k(const float* __restrict__ src, const float* __restrict__ cosT,
                             const float* __restrict__ sinT, u16* __restrict__ dst, float scale) {
  int p = blockIdx.x * 256 + threadIdx.x;     // 2^22 pairs
  int i = p & 31, h = (p >> 5) & 15, s = (p >> 9) & 2047, b = p >> 20;
  const float2 v = *reinterpret_cast<const float2*>(
      src + ((size_t)(b * 2048 + s) << 10) + h * 64 + 2 * i);
  float c = cosT[(s << 5) + i], sn = sinT[(s << 5) + i];
  float e = (v.x * c - v.y * sn) * scale;
  float o = (v.x * sn + v.y * c) * scale;
  u32 packed = pack_bf16(e, o);
  *reinterpret_cast<u32*>(dst + ((size_t)((b * 16 + h) * 2048 + s) << 6) + 2 * i) = packed;
}

// ---------- V transpose: tmp fp32 [b,s,h*64+dk] -> bf16 Vt [b,h,dk,s] ----------

__global__ void transpose_v_k(const float* __restrict__ src, u16* __restrict__ dst) {
  __shared__ float tile[64][65];
  int s0 = blockIdx.x * 64, bh = blockIdx.y;
  int b = bh >> 4, h = bh & 15;
  int tid = threadIdx.x;
  int c = tid & 63, r0 = tid >> 6;
  const float* sp = src + ((size_t)(b * 2048 + s0) << 10) + h * 64;
#pragma unroll
  for (int rr = 0; rr < 16; ++rr) {
    int r = rr * 4 + r0;
    tile[r][c] = sp[((size_t)r << 10) + c];
  }
  __syncthreads();
  u16* dp = dst + ((size_t)bh << 17) + s0;    // bh*64*2048
#pragma unroll
  for (int rr = 0; rr < 16; ++rr) {
    int dk = rr * 4 + r0;
    dp[((size_t)dk << 11) + c] = f2bf(tile[c][dk]);
  }
}

// ---------- GEMM: C(MxN fp32) = A(MxK bf16 rm) * B^T (B: NxK bf16 rm) ----------

__global__ __launch_bounds__(256, 2)
void gemm_bt(const u16* __restrict__ A, const u16* __restrict__ B,
             float* __restrict__ C, int M, int N, int K) {
  __shared__ u16 a_lds[2][128 * 32];
  __shared__ u16 b_lds[2][128 * 32];
  const int tid = threadIdx.x;
  const int l = tid & 63;
  const int w = tid >> 6;
  const int wm = w >> 1, wn = w & 1;
  const int bm = blockIdx.y, bn = blockIdx.x;

  const u16* Ab = A + (size_t)bm * 128 * K;
  const u16* Bb = B + (size_t)bn * 128 * K;

  auto stage = [&](int bq, int k0) {
#pragma unroll
    for (int half = 0; half < 2; ++half) {
      int t = half * 256 + tid;
      int row = t >> 2, slot = t & 3;
      int sp = slot ^ ((row >> 1) & 3);
      gl_lds16(Ab + (size_t)row * K + k0 + sp * 8, &a_lds[bq][t * 8]);
      gl_lds16(Bb + (size_t)row * K + k0 + sp * 8, &b_lds[bq][t * 8]);
    }
  };

  const f32x4 fz = {0.f, 0.f, 0.f, 0.f};
  f32x4 acc[4][4];
#pragma unroll
  for (int mi = 0; mi < 4; ++mi)
#pragma unroll
    for (int ni = 0; ni < 4; ++ni) acc[mi][ni] = fz;

  const int nk = K >> 5;
  stage(0, 0);
  int buf = 0;
  for (int kt = 0; kt < nk; ++kt) {
    __syncthreads();
    if (kt + 1 < nk) stage(buf ^ 1, (kt + 1) * 32);
    bf16x8 af[4], bf[4];
#pragma unroll
    for (int mi = 0; mi < 4; ++mi) {
      int row = wm * 64 + mi * 16 + (l & 15);
      int sp = (l >> 4) ^ ((row >> 1) & 3);
      af[mi] = *(const bf16x8*)&a_lds[buf][row * 32 + sp * 8];
    }
#pragma unroll
    for (int ni = 0; ni < 4; ++ni) {
      int row = wn * 64 + ni * 16 + (l & 15);
      int sp = (l >> 4) ^ ((row >> 1) & 3);
      bf[ni] = *(const bf16x8*)&b_lds[buf][row * 32 + sp * 8];
    }
#pragma unroll
    for (int mi = 0; mi < 4; ++mi)
#pragma unroll
      for (int ni = 0; ni < 4; ++ni)
        acc[mi][ni] = MFMA16(af[mi], bf[ni], acc[mi][ni]);
    buf ^= 1;
  }

#pragma unroll
  for (int mi = 0; mi < 4; ++mi) {
    int rbase = bm * 128 + wm * 64 + mi * 16 + ((l >> 4) << 2);
#pragma unroll
    for (int ni = 0; ni < 4; ++ni) {
      int col = bn * 128 + wn * 64 + ni * 16 + (l & 15);
      f32x4 v = acc[mi][ni];
#pragma unroll
      for (int j = 0; j < 4; ++j)
        C[(size_t)(rbase + j) * N + col] = v[j];
    }
  }
}

// ---------- causal flash attention (swapped-QK^T, in-register softmax) ----------
// Q: bf16 [b,h,s,64] pre-scaled by 0.125/ln2 (exp2 domain); K: bf16 [b,h,s,64];
// Vt: bf16 [b,h,dk,s]; O: bf16 [b,s,h*64+dk].
// Block = 4 waves; each wave owns 16 q-rows of a 64-row q-block; block processes
// q-block pair (p, 31-p) sequentially -> exactly 33 KV tiles per block (balanced).
// grid (16, B*H) = 1024 blocks = 4/CU.

__global__ __launch_bounds__(256, 4)
void attn_k(const u16* __restrict__ Q, const u16* __restrict__ K,
            const u16* __restrict__ V, u16* __restrict__ O) {
  const int S = 2048;
  __shared__ u16 q_lds[64 * 64];
  __shared__ u16 k_lds[2][64 * 64];
  __shared__ u16 v_lds[2][64 * 64];       // [dk][kv]

  const int tid = threadIdx.x, l = tid & 63, w = tid >> 6;
  const int c = l & 15, h = l >> 4;
  const int pairI = blockIdx.x, bh = blockIdx.y;
  const u16* Kb = K + (size_t)bh * S * 64;
  const u16* Vb = V + (size_t)bh * 64 * S;
  const int b = bh >> 4, hd = bh & 15;
  const f32x4 fz = {0.f, 0.f, 0.f, 0.f};

#pragma unroll 1
  for (int ph = 0; ph < 2; ++ph) {
    const int qi = ph ? (31 - pairI) : pairI;
    const int q0 = qi * 64;
    const int nkv = qi + 1;
    const u16* Qb = Q + ((size_t)bh * S + q0) * 64;

    // stage Q (8KB) + first KV tile (two 8KB tiles); all via global_load_lds
#pragma unroll
    for (int half = 0; half < 2; ++half) {
      int t = half * 256 + tid;
      int row = t >> 3, slot = t & 7;
      int sp = slot ^ (row & 7);
      gl_lds16(Qb + row * 64 + sp * 8, &q_lds[t * 8]);
      gl_lds16(Kb + (size_t)row * 64 + sp * 8, &k_lds[0][t * 8]);
      gl_lds16(Vb + (size_t)row * S + sp * 8, &v_lds[0][t * 8]);
    }
    __syncthreads();

    // hoist Q B-fragments (whole phase): col=q=w*16+c, k=d contiguous
    bf16x8 qf[2];
#pragma unroll
    for (int ks = 0; ks < 2; ++ks) {
      int row = w * 16 + c;
      int sp = (4 * ks + h) ^ (row & 7);
      qf[ks] = *(const bf16x8*)&q_lds[row * 64 + sp * 8];
    }

    f32x4 oacc[4];
#pragma unroll
    for (int ni = 0; ni < 4; ++ni) oacc[ni] = fz;
    float m_run = -1e30f, l_run = 0.f;

    int buf = 0;
    for (int t = 0; t < nkv; ++t) {
      // prefetch next KV tile into other buffer (overlaps with compute below)
      if (t + 1 < nkv) {
        int kv0 = (t + 1) * 64;
#pragma unroll
        for (int half = 0; half < 2; ++half) {
          int tt = half * 256 + tid;
          int row = tt >> 3, slot = tt & 7;
          int sp = slot ^ (row & 7);
          gl_lds16(Kb + (size_t)(kv0 + row) * 64 + sp * 8, &k_lds[buf ^ 1][tt * 8]);
          gl_lds16(Vb + (size_t)row * S + kv0 + sp * 8, &v_lds[buf ^ 1][tt * 8]);
        }
      }

      // S^T = K * Q^T : C[kv, q]; lane: q = q0 + w*16 + c, kv = t*64 + kvb*16 + 4h + j
      f32x4 sc[4];
#pragma unroll
      for (int kvb = 0; kvb < 4; ++kvb) sc[kvb] = fz;
#pragma unroll
      for (int ks = 0; ks < 2; ++ks)
#pragma unroll
        for (int kvb = 0; kvb < 4; ++kvb) {
          int row = kvb * 16 + c;
          int sp = (4 * ks + h) ^ (row & 7);
          bf16x8 kf = *(const bf16x8*)&k_lds[buf][row * 64 + sp * 8];
          sc[kvb] = MFMA16(kf, qf[ks], sc[kvb]);
        }

      // causal mask (only diagonal tile)
      if (t == qi) {
        int qg = q0 + w * 16 + c;
#pragma unroll
        for (int kvb = 0; kvb < 4; ++kvb)
#pragma unroll
          for (int j = 0; j < 4; ++j) {
            int kvg = t * 64 + kvb * 16 + 4 * h + j;
            if (kvg > qg) sc[kvb][j] = -1e30f;
          }
      }

      // online softmax (exp2 domain; row is lane-local, 2-shfl full-row reduce)
      float mx = -1e30f;
#pragma unroll
      for (int kvb = 0; kvb < 4; ++kvb)
#pragma unroll
        for (int j = 0; j < 4; ++j) mx = fmaxf(mx, sc[kvb][j]);
      mx = fmaxf(mx, __shfl_xor(mx, 16));
      mx = fmaxf(mx, __shfl_xor(mx, 32));

      const bool norescale = __all(mx <= m_run);
      float mnew = norescale ? m_run : fmaxf(m_run, mx);
      float ps = 0.f;
#pragma unroll
      for (int kvb = 0; kvb < 4; ++kvb)
#pragma unroll
        for (int j = 0; j < 4; ++j) {
          float e = exp2f(sc[kvb][j] - mnew);
          sc[kvb][j] = e;
          ps += e;
        }
      ps += __shfl_xor(ps, 16);
      ps += __shfl_xor(ps, 32);

      if (norescale) {
        l_run += ps;
      } else {
        float alpha = exp2f(m_run - mnew);
        l_run = l_run * alpha + ps;
        m_run = mnew;
        float aj[4];
#pragma unroll
        for (int j = 0; j < 4; ++j) aj[j] = __shfl(alpha, 20 * h + j);
#pragma unroll
        for (int ni = 0; ni < 4; ++ni)
#pragma unroll
          for (int j = 0; j < 4; ++j) oacc[ni][j] *= aj[j];
      }

      // pack P to bf16 pairs: pk[kvb][r] = (kv=16kvb+4h+2r, +1) for q-row c
      u32 pk[4][2];
#pragma unroll
      for (int kvb = 0; kvb < 4; ++kvb)
#pragma unroll
        for (int r = 0; r < 2; ++r)
          pk[kvb][r] = pack_bf16(sc[kvb][2 * r], sc[kvb][2 * r + 1]);

      // O += P * V : A-frag = P[q, kv] assembled via cross-lane shuffle
#pragma unroll
      for (int ks = 0; ks < 2; ++ks) {
        union { u32 u[4]; bf16x8 v; } af;
#pragma unroll
        for (int tt = 0; tt < 4; ++tt) {
          int src = ((l & 16) << 1) | ((tt >> 1) << 4) | c;
          u32 lo = (u32)__shfl((int)pk[2 * ks][tt & 1], src);
          u32 hi = (u32)__shfl((int)pk[2 * ks + 1][tt & 1], src);
          af.u[tt] = (l & 32) ? hi : lo;
        }
#pragma unroll
        for (int ni = 0; ni < 4; ++ni) {
          int row = ni * 16 + c;
          int sp = (4 * ks + h) ^ (row & 7);
          bf16x8 vf = *(const bf16x8*)&v_lds[buf][row * 64 + sp * 8];
          oacc[ni] = MFMA16(af.v, vf, oacc[ni]);
        }
      }

      __syncthreads();
      buf ^= 1;
    }

    // epilogue: normalize and write bf16 [b, s, hd*64+dk]; oacc row = 4h+j
    float invl[4];
#pragma unroll
    for (int j = 0; j < 4; ++j)
      invl[j] = 1.f / __shfl(l_run, 20 * h + j);
#pragma unroll
    for (int ni = 0; ni < 4; ++ni)
#pragma unroll
      for (int j = 0; j < 4; ++j) {
        int srow = q0 + w * 16 + 4 * h + j;
        int dk = ni * 16 + c;
        O[((size_t)(b * 2048 + srow) << 10) + hd * 64 + dk] = f2bf(oacc[ni][j] * invl[j]);
      }
    __syncthreads();   // protect q_lds/k_lds/v_lds before next phase restages
  }
}

// ---------- launch ----------

extern "C" void kernel_launch(void* const* d_in, const int* in_sizes, int n_in,
                              void* d_out, int out_size, void* d_ws, size_t ws_size,
                              hipStream_t stream) {
  (void)in_sizes; (void)n_in; (void)out_size; (void)ws_size;
  const float* x  = (const float*)d_in[0];
  const int* pos  = (const int*)d_in[1];
  const float* Wq = (const float*)d_in[2];
  const float* Wk = (const float*)d_in[3];
  const float* Wv = (const float*)d_in[4];
  const float* Wo = (const float*)d_in[5];
  float* out = (float*)d_out;

  const int S = 2048, D = 1024;
  const size_t M = (size_t)4 * S;          // 8192

  char* ws = (char*)d_ws;
  size_t off = 0;
  auto alloc = [&](size_t bytes) {
    void* p = ws + off;
    off += (bytes + 255) & ~(size_t)255;
    return p;
  };
  u16* xb   = (u16*)alloc(M * D * 2);
  u16* wqb  = (u16*)alloc((size_t)D * D * 2);
  u16* wkb  = (u16*)alloc((size_t)D * D * 2);
  u16* wvb  = (u16*)alloc((size_t)D * D * 2);
  u16* wob  = (u16*)alloc((size_t)D * D * 2);
  float* tmp = (float*)alloc(M * D * 4);
  u16* Qr   = (u16*)alloc(M * D * 2);
  u16* Kr   = (u16*)alloc(M * D * 2);
  u16* Vt   = (u16*)alloc(M * D * 2);
  u16* Ob   = (u16*)alloc(M * D * 2);
  float* cosT = (float*)alloc((size_t)S * 32 * 4);
  float* sinT = (float*)alloc((size_t)S * 32 * 4);

  const int nx4 = (int)(M * D / 4);        // 2M
  const int nw4 = D * D / 4;               // 256K
  cast_f32_bf16_v4<<<(nx4 + 255) / 256, 256, 0, stream>>>(x, xb, nx4);
  cast_f32_bf16_v4<<<(nw4 + 255) / 256, 256, 0, stream>>>(Wq, wqb, nw4);
  cast_f32_bf16_v4<<<(nw4 + 255) / 256, 256, 0, stream>>>(Wk, wkb, nw4);
  cast_f32_bf16_v4<<<(nw4 + 255) / 256, 256, 0, stream>>>(Wv, wvb, nw4);
  cast_f32_bf16_v4<<<(nw4 + 255) / 256, 256, 0, stream>>>(Wo, wob, nw4);
  rope_table_k<<<(S * 32) / 256, 256, 0, stream>>>(pos, cosT, sinT);

  dim3 ggrid(D / 128, (unsigned)(M / 128));   // (8, 64)
  const int nrope = (int)(M * D / 2 / 256);   // 16384 blocks of 256 pairs

  // Q scale: 1/sqrt(64) folded with 1/ln2 so attention logits are in exp2 domain
  const float QSCALE = 0.125f * 1.4426950408889634f;

  gemm_bt<<<ggrid, 256, 0, stream>>>(xb, wqb, tmp, (int)M, D, D);
  rope_apply_k<<<nrope, 256, 0, stream>>>(tmp, cosT, sinT, Qr, QSCALE);
  gemm_bt<<<ggrid, 256, 0, stream>>>(xb, wkb, tmp, (int)M, D, D);
  rope_apply_k<<<nrope, 256, 0, stream>>>(tmp, cosT, sinT, Kr, 1.0f);
  gemm_bt<<<ggrid, 256, 0, stream>>>(xb, wvb, tmp, (int)M, D, D);
  transpose_v_k<<<dim3(S / 64, 64), 256, 0, stream>>>(tmp, Vt);
  attn_k<<<dim3(16, 64), 256, 0, stream>>>(Qr, Kr, Vt, Ob);
  gemm_bt<<<ggrid, 256, 0, stream>>>(Ob, wob, out, (int)M, D, D);
}

// Round 4
// 214.104 us; speedup vs baseline: 1.8725x; 1.1716x over previous
//
#include <hip/hip_runtime.h>
#include <hip/hip_bf16.h>
#include <cstdint>
#include <cstddef>

typedef __attribute__((ext_vector_type(4))) float f32x4;
typedef __attribute__((ext_vector_type(8))) short bf16x8;
typedef unsigned int u32;
typedef unsigned short u16;

// ---------- helpers ----------

__device__ __forceinline__ u16 f2bf(float x) {
  u32 u = __builtin_bit_cast(u32, x);
  u += 0x7fffu + ((u >> 16) & 1u);   // round-to-nearest-even
  return (u16)(u >> 16);
}

// hardware packed f32x2 -> bf16x2 (low <- lo, high <- hi)
__device__ __forceinline__ u32 cvt_pk_bf16(float lo, float hi) {
  u32 r;
  asm("v_cvt_pk_bf16_f32 %0, %1, %2" : "=v"(r) : "v"(lo), "v"(hi));
  return r;
}

// async global->LDS, 16B per lane. Dest must be wave-linear (base + lane*16).
__device__ __forceinline__ void gl_lds16(const void* g, void* l) {
  __builtin_amdgcn_global_load_lds(
      (const __attribute__((address_space(1))) u32*)(uintptr_t)g,
      (__attribute__((address_space(3))) u32*)(u32)(uintptr_t)l,
      16, 0, 0);
}

#define MFMA16(a, b, c) __builtin_amdgcn_mfma_f32_16x16x32_bf16((a), (b), (c), 0, 0, 0)

// ---------- cast fp32 -> bf16 (vectorized x4) ----------

__global__ void cast_f32_bf16_v4(const float* __restrict__ src, u16* __restrict__ dst, int n4) {
  int i = blockIdx.x * 256 + threadIdx.x;
  if (i >= n4) return;
  const float4 v = reinterpret_cast<const float4*>(src)[i];
  union { u16 s[4]; uint2 u; } o;
  o.s[0] = f2bf(v.x); o.s[1] = f2bf(v.y); o.s[2] = f2bf(v.z); o.s[3] = f2bf(v.w);
  reinterpret_cast<uint2*>(dst)[i] = o.u;
}

// ---------- rope cos/sin table: [S][32] of float2(cos,sin) ----------

__global__ void rope_table_k(const int* __restrict__ pos, float2* __restrict__ cs) {
  int idx = blockIdx.x * 256 + threadIdx.x;   // S*32 = 65536
  int s = idx >> 5, i = idx & 31;
  float inv = powf(10000.0f, -(float)i * (1.0f / 32.0f));
  float ang = (float)pos[s] * inv;
  cs[idx] = float2{cosf(ang), sinf(ang)};
}

// ---------- fused QKV GEMM ----------
// A: xb [8192,1024] bf16; B: Wq|Wk|Wv stacked [3072,1024] bf16 (row-major, B^T GEMM)
// Epilogue: bn 0-7 -> rope+scale -> Qr [b,h,s,64]; bn 8-15 -> rope -> Kr;
//           bn 16-23 -> transpose -> Vt [b,h,dk,s]. All bf16.

__global__ __launch_bounds__(256, 2)
void gemm_qkv(const u16* __restrict__ A, const u16* __restrict__ B,
              const float2* __restrict__ cs, u16* __restrict__ Qr,
              u16* __restrict__ Kr, u16* __restrict__ Vt, float qscale) {
  const int K = 1024;
  __shared__ u16 a_lds[2][128 * 32];
  __shared__ u16 b_lds[2][128 * 32];
  const int tid = threadIdx.x;
  const int l = tid & 63;
  const int w = tid >> 6;
  const int wm = w >> 1, wn = w & 1;
  const int bm = blockIdx.y, bn = blockIdx.x;

  const u16* Ab = A + (size_t)bm * 128 * K;
  const u16* Bb = B + (size_t)bn * 128 * K;

  auto stage = [&](int bq, int k0) {
#pragma unroll
    for (int half = 0; half < 2; ++half) {
      int t = half * 256 + tid;
      int row = t >> 2, slot = t & 3;
      int sp = slot ^ ((row >> 1) & 3);
      gl_lds16(Ab + (size_t)row * K + k0 + sp * 8, &a_lds[bq][t * 8]);
      gl_lds16(Bb + (size_t)row * K + k0 + sp * 8, &b_lds[bq][t * 8]);
    }
  };

  const f32x4 fz = {0.f, 0.f, 0.f, 0.f};
  f32x4 acc[4][4];
#pragma unroll
  for (int mi = 0; mi < 4; ++mi)
#pragma unroll
    for (int ni = 0; ni < 4; ++ni) acc[mi][ni] = fz;

  const int nk = K >> 5;
  stage(0, 0);
  int buf = 0;
  for (int kt = 0; kt < nk; ++kt) {
    __syncthreads();
    if (kt + 1 < nk) stage(buf ^ 1, (kt + 1) * 32);
    bf16x8 af[4], bf[4];
#pragma unroll
    for (int mi = 0; mi < 4; ++mi) {
      int row = wm * 64 + mi * 16 + (l & 15);
      int sp = (l >> 4) ^ ((row >> 1) & 3);
      af[mi] = *(const bf16x8*)&a_lds[buf][row * 32 + sp * 8];
    }
#pragma unroll
    for (int ni = 0; ni < 4; ++ni) {
      int row = wn * 64 + ni * 16 + (l & 15);
      int sp = (l >> 4) ^ ((row >> 1) & 3);
      bf[ni] = *(const bf16x8*)&b_lds[buf][row * 32 + sp * 8];
    }
#pragma unroll
    for (int mi = 0; mi < 4; ++mi)
#pragma unroll
      for (int ni = 0; ni < 4; ++ni)
        acc[mi][ni] = MFMA16(af[mi], bf[ni], acc[mi][ni]);
    buf ^= 1;
  }

  // ---- epilogue ----
  const int sector = bn >> 3;                     // 0:Q 1:K 2:V (block-uniform)
  const int colb = ((bn & 7) << 7) + wn * 64;     // col within 1024-wide sector
  const int c = l & 15, h4 = l >> 4;

  if (sector == 2) {
    // V: transposed bf16 write Vt[b,h,dk,s]
#pragma unroll
    for (int mi = 0; mi < 4; ++mi) {
      int row = bm * 128 + wm * 64 + mi * 16 + 4 * h4;   // global row (b*2048+s)
      int b_ = row >> 11, s = row & 2047;                // rows row..row+3 same batch
#pragma unroll
      for (int ni = 0; ni < 4; ++ni) {
        int cv = colb + ni * 16 + c;
        int hh = cv >> 6, dk = cv & 63;
        f32x4 v = acc[mi][ni];
        uint2 st;
        st.x = cvt_pk_bf16(v[0], v[1]);
        st.y = cvt_pk_bf16(v[2], v[3]);
        *(uint2*)&Vt[(((size_t)b_ * 16 + hh) << 17) + ((size_t)dk << 11) + s] = st;
      }
    }
  } else {
    u16* dst = sector ? Kr : Qr;
    const float scale = sector ? 1.0f : qscale;
#pragma unroll
    for (int mi = 0; mi < 4; ++mi) {
      int row0 = bm * 128 + wm * 64 + mi * 16 + 4 * h4;
#pragma unroll
      for (int ni = 0; ni < 4; ++ni) {
        int cv = colb + ni * 16 + c;
        int hh = cv >> 6, i2 = cv & 63;
        f32x4 v = acc[mi][ni];
        f32x4 pv;
#pragma unroll
        for (int j = 0; j < 4; ++j) pv[j] = __shfl_xor(v[j], 1);
        if (!(l & 1)) {                          // even lanes write the (even,odd) pair
#pragma unroll
          for (int j = 0; j < 4; ++j) {
            int r = row0 + j, s = r & 2047, b_ = r >> 11;
            float2 t = cs[(s << 5) + (i2 >> 1)];
            float oe = (v[j] * t.x - pv[j] * t.y) * scale;
            float oo = (v[j] * t.y + pv[j] * t.x) * scale;
            *(u32*)&dst[(((size_t)(b_ * 16 + hh) * 2048 + s) << 6) + i2] =
                cvt_pk_bf16(oe, oo);
          }
        }
      }
    }
  }
}

// ---------- GEMM: C(MxN fp32) = A(MxK bf16 rm) * B^T (B: NxK bf16 rm) ----------

__global__ __launch_bounds__(256, 2)
void gemm_bt(const u16* __restrict__ A, const u16* __restrict__ B,
             float* __restrict__ C, int M, int N, int K) {
  __shared__ u16 a_lds[2][128 * 32];
  __shared__ u16 b_lds[2][128 * 32];
  const int tid = threadIdx.x;
  const int l = tid & 63;
  const int w = tid >> 6;
  const int wm = w >> 1, wn = w & 1;
  const int bm = blockIdx.y, bn = blockIdx.x;

  const u16* Ab = A + (size_t)bm * 128 * K;
  const u16* Bb = B + (size_t)bn * 128 * K;

  auto stage = [&](int bq, int k0) {
#pragma unroll
    for (int half = 0; half < 2; ++half) {
      int t = half * 256 + tid;
      int row = t >> 2, slot = t & 3;
      int sp = slot ^ ((row >> 1) & 3);
      gl_lds16(Ab + (size_t)row * K + k0 + sp * 8, &a_lds[bq][t * 8]);
      gl_lds16(Bb + (size_t)row * K + k0 + sp * 8, &b_lds[bq][t * 8]);
    }
  };

  const f32x4 fz = {0.f, 0.f, 0.f, 0.f};
  f32x4 acc[4][4];
#pragma unroll
  for (int mi = 0; mi < 4; ++mi)
#pragma unroll
    for (int ni = 0; ni < 4; ++ni) acc[mi][ni] = fz;

  const int nk = K >> 5;
  stage(0, 0);
  int buf = 0;
  for (int kt = 0; kt < nk; ++kt) {
    __syncthreads();
    if (kt + 1 < nk) stage(buf ^ 1, (kt + 1) * 32);
    bf16x8 af[4], bf[4];
#pragma unroll
    for (int mi = 0; mi < 4; ++mi) {
      int row = wm * 64 + mi * 16 + (l & 15);
      int sp = (l >> 4) ^ ((row >> 1) & 3);
      af[mi] = *(const bf16x8*)&a_lds[buf][row * 32 + sp * 8];
    }
#pragma unroll
    for (int ni = 0; ni < 4; ++ni) {
      int row = wn * 64 + ni * 16 + (l & 15);
      int sp = (l >> 4) ^ ((row >> 1) & 3);
      bf[ni] = *(const bf16x8*)&b_lds[buf][row * 32 + sp * 8];
    }
#pragma unroll
    for (int mi = 0; mi < 4; ++mi)
#pragma unroll
      for (int ni = 0; ni < 4; ++ni)
        acc[mi][ni] = MFMA16(af[mi], bf[ni], acc[mi][ni]);
    buf ^= 1;
  }

#pragma unroll
  for (int mi = 0; mi < 4; ++mi) {
    int rbase = bm * 128 + wm * 64 + mi * 16 + ((l >> 4) << 2);
#pragma unroll
    for (int ni = 0; ni < 4; ++ni) {
      int col = bn * 128 + wn * 64 + ni * 16 + (l & 15);
      f32x4 v = acc[mi][ni];
#pragma unroll
      for (int j = 0; j < 4; ++j)
        C[(size_t)(rbase + j) * N + col] = v[j];
    }
  }
}

// ---------- causal flash attention (swapped-QK^T, in-register softmax) ----------
// Q: bf16 [b,h,s,64] pre-scaled by 0.125/ln2 (exp2 domain); K: bf16 [b,h,s,64];
// Vt: bf16 [b,h,dk,s]; O: bf16 [b,s,h*64+dk].
// 1D grid 1024 blocks, bh-grouped XCD swizzle (8 bh per XCD for K/V L2 locality).
// Block = 4 waves; each wave owns 16 q-rows of a 64-row q-block; block processes
// q-block pair (p, 31-p) sequentially -> exactly 33 KV tiles per block (balanced).

__global__ __launch_bounds__(256, 4)
void attn_k(const u16* __restrict__ Q, const u16* __restrict__ K,
            const u16* __restrict__ V, u16* __restrict__ O) {
  const int S = 2048;
  __shared__ u16 q_lds[64 * 64];
  __shared__ u16 k_lds[2][64 * 64];
  __shared__ u16 v_lds[2][64 * 64];       // [dk][kv]

  const int tid = threadIdx.x, l = tid & 63, w = tid >> 6;
  const int c = l & 15, h = l >> 4;

  // bijective XCD swizzle: XCD x gets bh in [8x, 8x+8)
  const int wg = blockIdx.x;                       // 1024
  const int idx = (wg & 7) * 128 + (wg >> 3);
  const int bh = idx >> 4, pairI = idx & 15;

  const u16* Kb = K + (size_t)bh * S * 64;
  const u16* Vb = V + (size_t)bh * 64 * S;
  const int b = bh >> 4, hd = bh & 15;
  const f32x4 fz = {0.f, 0.f, 0.f, 0.f};

  // loop-invariant bpermute lane addresses for PV A-frag assembly
  int bperm[4];
#pragma unroll
  for (int tt = 0; tt < 4; ++tt)
    bperm[tt] = ((((l & 16) << 1) | ((tt >> 1) << 4) | c) << 2);

#pragma unroll 1
  for (int ph = 0; ph < 2; ++ph) {
    const int qi = ph ? (31 - pairI) : pairI;
    const int q0 = qi * 64;
    const int nkv = qi + 1;
    const u16* Qb = Q + ((size_t)bh * S + q0) * 64;

    // stage Q (8KB) + first KV tile; all via global_load_lds
#pragma unroll
    for (int half = 0; half < 2; ++half) {
      int t = half * 256 + tid;
      int row = t >> 3, slot = t & 7;
      int sp = slot ^ (row & 7);
      gl_lds16(Qb + row * 64 + sp * 8, &q_lds[t * 8]);
      gl_lds16(Kb + (size_t)row * 64 + sp * 8, &k_lds[0][t * 8]);
      gl_lds16(Vb + (size_t)row * S + sp * 8, &v_lds[0][t * 8]);
    }
    __syncthreads();

    // hoist Q B-fragments (whole phase): col=q=w*16+c, k=d contiguous
    bf16x8 qf[2];
#pragma unroll
    for (int ks = 0; ks < 2; ++ks) {
      int row = w * 16 + c;
      int sp = (4 * ks + h) ^ (row & 7);
      qf[ks] = *(const bf16x8*)&q_lds[row * 64 + sp * 8];
    }

    f32x4 oacc[4];
#pragma unroll
    for (int ni = 0; ni < 4; ++ni) oacc[ni] = fz;
    float m_run = -1e30f, l_run = 0.f;

    int buf = 0;
    for (int t = 0; t < nkv; ++t) {
      // prefetch next KV tile into other buffer (overlaps with compute below)
      if (t + 1 < nkv) {
        int kv0 = (t + 1) * 64;
#pragma unroll
        for (int half = 0; half < 2; ++half) {
          int tt = half * 256 + tid;
          int row = tt >> 3, slot = tt & 7;
          int sp = slot ^ (row & 7);
          gl_lds16(Kb + (size_t)(kv0 + row) * 64 + sp * 8, &k_lds[buf ^ 1][tt * 8]);
          gl_lds16(Vb + (size_t)row * S + kv0 + sp * 8, &v_lds[buf ^ 1][tt * 8]);
        }
      }

      // S^T = K * Q^T : C[kv, q]; lane: q = q0 + w*16 + c, kv = t*64 + kvb*16 + 4h + j
      f32x4 sc[4];
#pragma unroll
      for (int kvb = 0; kvb < 4; ++kvb) sc[kvb] = fz;
#pragma unroll
      for (int ks = 0; ks < 2; ++ks)
#pragma unroll
        for (int kvb = 0; kvb < 4; ++kvb) {
          int row = kvb * 16 + c;
          int sp = (4 * ks + h) ^ (row & 7);
          bf16x8 kf = *(const bf16x8*)&k_lds[buf][row * 64 + sp * 8];
          sc[kvb] = MFMA16(kf, qf[ks], sc[kvb]);
        }

      // causal mask (only diagonal tile)
      if (t == qi) {
        int qg = q0 + w * 16 + c;
#pragma unroll
        for (int kvb = 0; kvb < 4; ++kvb)
#pragma unroll
          for (int j = 0; j < 4; ++j) {
            int kvg = t * 64 + kvb * 16 + 4 * h + j;
            if (kvg > qg) sc[kvb][j] = -1e30f;
          }
      }

      // online softmax (exp2 domain; row is lane-local, 2-shfl full-row reduce)
      float mx = -1e30f;
#pragma unroll
      for (int kvb = 0; kvb < 4; ++kvb)
#pragma unroll
        for (int j = 0; j < 4; ++j) mx = fmaxf(mx, sc[kvb][j]);
      mx = fmaxf(mx, __shfl_xor(mx, 16));
      mx = fmaxf(mx, __shfl_xor(mx, 32));

      const bool norescale = __all(mx <= m_run);
      float mnew = norescale ? m_run : fmaxf(m_run, mx);
      float ps = 0.f;
#pragma unroll
      for (int kvb = 0; kvb < 4; ++kvb)
#pragma unroll
        for (int j = 0; j < 4; ++j) {
          float e = exp2f(sc[kvb][j] - mnew);
          sc[kvb][j] = e;
          ps += e;
        }
      ps += __shfl_xor(ps, 16);
      ps += __shfl_xor(ps, 32);

      if (norescale) {
        l_run += ps;
      } else {
        float alpha = exp2f(m_run - mnew);
        l_run = l_run * alpha + ps;
        m_run = mnew;
        float aj[4];
#pragma unroll
        for (int j = 0; j < 4; ++j) aj[j] = __shfl(alpha, 20 * h + j);
#pragma unroll
        for (int ni = 0; ni < 4; ++ni)
#pragma unroll
          for (int j = 0; j < 4; ++j) oacc[ni][j] *= aj[j];
      }

      // pack P to bf16 pairs via hardware cvt_pk
      u32 pk[4][2];
#pragma unroll
      for (int kvb = 0; kvb < 4; ++kvb) {
        pk[kvb][0] = cvt_pk_bf16(sc[kvb][0], sc[kvb][1]);
        pk[kvb][1] = cvt_pk_bf16(sc[kvb][2], sc[kvb][3]);
      }

      // O += P * V : A-frag = P[q, kv] assembled via ds_bpermute (hoisted addrs)
#pragma unroll
      for (int ks = 0; ks < 2; ++ks) {
        union { u32 u[4]; bf16x8 v; } af;
#pragma unroll
        for (int tt = 0; tt < 4; ++tt) {
          u32 lo = (u32)__builtin_amdgcn_ds_bpermute(bperm[tt], (int)pk[2 * ks][tt & 1]);
          u32 hi = (u32)__builtin_amdgcn_ds_bpermute(bperm[tt], (int)pk[2 * ks + 1][tt & 1]);
          af.u[tt] = (l & 32) ? hi : lo;
        }
#pragma unroll
        for (int ni = 0; ni < 4; ++ni) {
          int row = ni * 16 + c;
          int sp = (4 * ks + h) ^ (row & 7);
          bf16x8 vf = *(const bf16x8*)&v_lds[buf][row * 64 + sp * 8];
          oacc[ni] = MFMA16(af.v, vf, oacc[ni]);
        }
      }

      __syncthreads();
      buf ^= 1;
    }

    // epilogue: normalize and write bf16 [b, s, hd*64+dk]; oacc row = 4h+j
    float invl[4];
#pragma unroll
    for (int j = 0; j < 4; ++j)
      invl[j] = 1.f / __shfl(l_run, 20 * h + j);
#pragma unroll
    for (int ni = 0; ni < 4; ++ni)
#pragma unroll
      for (int j = 0; j < 4; ++j) {
        int srow = q0 + w * 16 + 4 * h + j;
        int dk = ni * 16 + c;
        O[((size_t)(b * 2048 + srow) << 10) + hd * 64 + dk] = f2bf(oacc[ni][j] * invl[j]);
      }
    __syncthreads();   // protect q_lds/k_lds/v_lds before next phase restages
  }
}

// ---------- launch ----------

extern "C" void kernel_launch(void* const* d_in, const int* in_sizes, int n_in,
                              void* d_out, int out_size, void* d_ws, size_t ws_size,
                              hipStream_t stream) {
  (void)in_sizes; (void)n_in; (void)out_size; (void)ws_size;
  const float* x  = (const float*)d_in[0];
  const int* pos  = (const int*)d_in[1];
  const float* Wq = (const float*)d_in[2];
  const float* Wk = (const float*)d_in[3];
  const float* Wv = (const float*)d_in[4];
  const float* Wo = (const float*)d_in[5];
  float* out = (float*)d_out;

  const int S = 2048, D = 1024;
  const size_t M = (size_t)4 * S;          // 8192

  char* ws = (char*)d_ws;
  size_t off = 0;
  auto alloc = [&](size_t bytes) {
    void* p = ws + off;
    off += (bytes + 255) & ~(size_t)255;
    return p;
  };
  u16* xb   = (u16*)alloc(M * D * 2);
  u16* wqb  = (u16*)alloc((size_t)D * D * 2);   // wqb|wkb|wvb contiguous (2MB each)
  u16* wkb  = (u16*)alloc((size_t)D * D * 2);
  u16* wvb  = (u16*)alloc((size_t)D * D * 2);
  u16* wob  = (u16*)alloc((size_t)D * D * 2);
  u16* Qr   = (u16*)alloc(M * D * 2);
  u16* Kr   = (u16*)alloc(M * D * 2);
  u16* Vt   = (u16*)alloc(M * D * 2);
  u16* Ob   = (u16*)alloc(M * D * 2);
  float2* csT = (float2*)alloc((size_t)S * 32 * 8);

  const int nx4 = (int)(M * D / 4);        // 2M
  const int nw4 = D * D / 4;               // 256K
  cast_f32_bf16_v4<<<(nx4 + 255) / 256, 256, 0, stream>>>(x, xb, nx4);
  cast_f32_bf16_v4<<<(nw4 + 255) / 256, 256, 0, stream>>>(Wq, wqb, nw4);
  cast_f32_bf16_v4<<<(nw4 + 255) / 256, 256, 0, stream>>>(Wk, wkb, nw4);
  cast_f32_bf16_v4<<<(nw4 + 255) / 256, 256, 0, stream>>>(Wv, wvb, nw4);
  cast_f32_bf16_v4<<<(nw4 + 255) / 256, 256, 0, stream>>>(Wo, wob, nw4);
  rope_table_k<<<(S * 32) / 256, 256, 0, stream>>>(pos, csT);

  // Q scale: 1/sqrt(64) folded with 1/ln2 so attention logits are in exp2 domain
  const float QSCALE = 0.125f * 1.4426950408889634f;

  gemm_qkv<<<dim3(24, (unsigned)(M / 128)), 256, 0, stream>>>(
      xb, wqb, csT, Qr, Kr, Vt, QSCALE);
  attn_k<<<1024, 256, 0, stream>>>(Qr, Kr, Vt, Ob);
  gemm_bt<<<dim3(8, (unsigned)(M / 128)), 256, 0, stream>>>(Ob, wob, out, (int)M, D, D);
}

// Round 5
// 207.595 us; speedup vs baseline: 1.9313x; 1.0314x over previous
//
#include <hip/hip_runtime.h>
#include <hip/hip_bf16.h>
#include <cstdint>
#include <cstddef>

typedef __attribute__((ext_vector_type(4))) float f32x4;
typedef __attribute__((ext_vector_type(8))) short bf16x8;
typedef unsigned int u32;
typedef unsigned short u16;

// ---------- helpers ----------

__device__ __forceinline__ u16 f2bf(float x) {
  u32 u = __builtin_bit_cast(u32, x);
  u += 0x7fffu + ((u >> 16) & 1u);   // round-to-nearest-even
  return (u16)(u >> 16);
}

// hardware packed f32x2 -> bf16x2 (low <- lo, high <- hi)
__device__ __forceinline__ u32 cvt_pk_bf16(float lo, float hi) {
  u32 r;
  asm("v_cvt_pk_bf16_f32 %0, %1, %2" : "=v"(r) : "v"(lo), "v"(hi));
  return r;
}

// async global->LDS, 16B per lane. Dest must be wave-linear (base + lane*16).
__device__ __forceinline__ void gl_lds16(const void* g, void* l) {
  __builtin_amdgcn_global_load_lds(
      (const __attribute__((address_space(1))) u32*)(uintptr_t)g,
      (__attribute__((address_space(3))) u32*)(u32)(uintptr_t)l,
      16, 0, 0);
}

#define MFMA16(a, b, c) __builtin_amdgcn_mfma_f32_16x16x32_bf16((a), (b), (c), 0, 0, 0)

// ---------- fused cast fp32 -> bf16 for x + 4 weights ----------

__global__ void cast_all_k(const float* __restrict__ x, const float* __restrict__ wq,
                           const float* __restrict__ wk, const float* __restrict__ wv,
                           const float* __restrict__ wo, u16* __restrict__ xb,
                           u16* __restrict__ wqb, u16* __restrict__ wkb,
                           u16* __restrict__ wvb, u16* __restrict__ wob) {
  int blk = blockIdx.x;
  const float* s; u16* d; int i;
  if (blk < 8192)       { s = x;  d = xb;  i = blk * 256; }
  else if (blk < 9216)  { s = wq; d = wqb; i = (blk - 8192) * 256; }
  else if (blk < 10240) { s = wk; d = wkb; i = (blk - 9216) * 256; }
  else if (blk < 11264) { s = wv; d = wvb; i = (blk - 10240) * 256; }
  else                  { s = wo; d = wob; i = (blk - 11264) * 256; }
  i += threadIdx.x;
  const float4 v = reinterpret_cast<const float4*>(s)[i];
  uint2 o;
  o.x = cvt_pk_bf16(v.x, v.y);
  o.y = cvt_pk_bf16(v.z, v.w);
  reinterpret_cast<uint2*>(d)[i] = o;
}

// ---------- rope cos/sin table: [S][32] of float2(cos,sin) ----------

__global__ void rope_table_k(const int* __restrict__ pos, float2* __restrict__ cs) {
  int idx = blockIdx.x * 256 + threadIdx.x;   // S*32 = 65536
  int s = idx >> 5, i = idx & 31;
  float inv = powf(10000.0f, -(float)i * (1.0f / 32.0f));
  float ang = (float)pos[s] * inv;
  cs[idx] = float2{cosf(ang), sinf(ang)};
}

// ---------- fused QKV GEMM ----------
// A: xb [8192,1024] bf16; B: Wq|Wk|Wv stacked [3072,1024] bf16 (row-major, B^T GEMM)
// Epilogue: bn 0-7 -> rope+scale -> Qr [b,h,s,64]; bn 8-15 -> rope -> Kr;
//           bn 16-23 -> transpose -> Vt [b,h,dk,s]. All bf16.

__global__ __launch_bounds__(256, 2)
void gemm_qkv(const u16* __restrict__ A, const u16* __restrict__ B,
              const float2* __restrict__ cs, u16* __restrict__ Qr,
              u16* __restrict__ Kr, u16* __restrict__ Vt, float qscale) {
  const int K = 1024;
  __shared__ u16 a_lds[2][128 * 32];
  __shared__ u16 b_lds[2][128 * 32];
  const int tid = threadIdx.x;
  const int l = tid & 63;
  const int w = tid >> 6;
  const int wm = w >> 1, wn = w & 1;
  const int bm = blockIdx.y, bn = blockIdx.x;

  const u16* Ab = A + (size_t)bm * 128 * K;
  const u16* Bb = B + (size_t)bn * 128 * K;

  auto stage = [&](int bq, int k0) {
#pragma unroll
    for (int half = 0; half < 2; ++half) {
      int t = half * 256 + tid;
      int row = t >> 2, slot = t & 3;
      int sp = slot ^ ((row >> 1) & 3);
      gl_lds16(Ab + (size_t)row * K + k0 + sp * 8, &a_lds[bq][t * 8]);
      gl_lds16(Bb + (size_t)row * K + k0 + sp * 8, &b_lds[bq][t * 8]);
    }
  };

  const f32x4 fz = {0.f, 0.f, 0.f, 0.f};
  f32x4 acc[4][4];
#pragma unroll
  for (int mi = 0; mi < 4; ++mi)
#pragma unroll
    for (int ni = 0; ni < 4; ++ni) acc[mi][ni] = fz;

  const int nk = K >> 5;
  stage(0, 0);
  int buf = 0;
  for (int kt = 0; kt < nk; ++kt) {
    __syncthreads();
    if (kt + 1 < nk) stage(buf ^ 1, (kt + 1) * 32);
    bf16x8 af[4], bf[4];
#pragma unroll
    for (int mi = 0; mi < 4; ++mi) {
      int row = wm * 64 + mi * 16 + (l & 15);
      int sp = (l >> 4) ^ ((row >> 1) & 3);
      af[mi] = *(const bf16x8*)&a_lds[buf][row * 32 + sp * 8];
    }
#pragma unroll
    for (int ni = 0; ni < 4; ++ni) {
      int row = wn * 64 + ni * 16 + (l & 15);
      int sp = (l >> 4) ^ ((row >> 1) & 3);
      bf[ni] = *(const bf16x8*)&b_lds[buf][row * 32 + sp * 8];
    }
#pragma unroll
    for (int mi = 0; mi < 4; ++mi)
#pragma unroll
      for (int ni = 0; ni < 4; ++ni)
        acc[mi][ni] = MFMA16(af[mi], bf[ni], acc[mi][ni]);
    buf ^= 1;
  }

  // ---- epilogue ----
  const int sector = bn >> 3;                     // 0:Q 1:K 2:V (block-uniform)
  const int colb = ((bn & 7) << 7) + wn * 64;     // col within 1024-wide sector
  const int c = l & 15, h4 = l >> 4;

  if (sector == 2) {
    // V: transposed bf16 write Vt[b,h,dk,s]
#pragma unroll
    for (int mi = 0; mi < 4; ++mi) {
      int row = bm * 128 + wm * 64 + mi * 16 + 4 * h4;   // global row (b*2048+s)
      int b_ = row >> 11, s = row & 2047;
#pragma unroll
      for (int ni = 0; ni < 4; ++ni) {
        int cv = colb + ni * 16 + c;
        int hh = cv >> 6, dk = cv & 63;
        f32x4 v = acc[mi][ni];
        uint2 st;
        st.x = cvt_pk_bf16(v[0], v[1]);
        st.y = cvt_pk_bf16(v[2], v[3]);
        *(uint2*)&Vt[(((size_t)b_ * 16 + hh) << 17) + ((size_t)dk << 11) + s] = st;
      }
    }
  } else {
    u16* dst = sector ? Kr : Qr;
    const float scale = sector ? 1.0f : qscale;
#pragma unroll
    for (int mi = 0; mi < 4; ++mi) {
      int row0 = bm * 128 + wm * 64 + mi * 16 + 4 * h4;
#pragma unroll
      for (int ni = 0; ni < 4; ++ni) {
        int cv = colb + ni * 16 + c;
        int hh = cv >> 6, i2 = cv & 63;
        f32x4 v = acc[mi][ni];
        f32x4 pv;
#pragma unroll
        for (int j = 0; j < 4; ++j) pv[j] = __shfl_xor(v[j], 1);
        if (!(l & 1)) {                          // even lanes write the (even,odd) pair
#pragma unroll
          for (int j = 0; j < 4; ++j) {
            int r = row0 + j, s = r & 2047, b_ = r >> 11;
            float2 t = cs[(s << 5) + (i2 >> 1)];
            float oe = (v[j] * t.x - pv[j] * t.y) * scale;
            float oo = (v[j] * t.y + pv[j] * t.x) * scale;
            *(u32*)&dst[(((size_t)(b_ * 16 + hh) * 2048 + s) << 6) + i2] =
                cvt_pk_bf16(oe, oo);
          }
        }
      }
    }
  }
}

// ---------- GEMM: C(MxN fp32) = A(MxK bf16 rm) * B^T (B: NxK bf16 rm) ----------

__global__ __launch_bounds__(256, 2)
void gemm_bt(const u16* __restrict__ A, const u16* __restrict__ B,
             float* __restrict__ C, int M, int N, int K) {
  __shared__ u16 a_lds[2][128 * 32];
  __shared__ u16 b_lds[2][128 * 32];
  const int tid = threadIdx.x;
  const int l = tid & 63;
  const int w = tid >> 6;
  const int wm = w >> 1, wn = w & 1;
  const int bm = blockIdx.y, bn = blockIdx.x;

  const u16* Ab = A + (size_t)bm * 128 * K;
  const u16* Bb = B + (size_t)bn * 128 * K;

  auto stage = [&](int bq, int k0) {
#pragma unroll
    for (int half = 0; half < 2; ++half) {
      int t = half * 256 + tid;
      int row = t >> 2, slot = t & 3;
      int sp = slot ^ ((row >> 1) & 3);
      gl_lds16(Ab + (size_t)row * K + k0 + sp * 8, &a_lds[bq][t * 8]);
      gl_lds16(Bb + (size_t)row * K + k0 + sp * 8, &b_lds[bq][t * 8]);
    }
  };

  const f32x4 fz = {0.f, 0.f, 0.f, 0.f};
  f32x4 acc[4][4];
#pragma unroll
  for (int mi = 0; mi < 4; ++mi)
#pragma unroll
    for (int ni = 0; ni < 4; ++ni) acc[mi][ni] = fz;

  const int nk = K >> 5;
  stage(0, 0);
  int buf = 0;
  for (int kt = 0; kt < nk; ++kt) {
    __syncthreads();
    if (kt + 1 < nk) stage(buf ^ 1, (kt + 1) * 32);
    bf16x8 af[4], bf[4];
#pragma unroll
    for (int mi = 0; mi < 4; ++mi) {
      int row = wm * 64 + mi * 16 + (l & 15);
      int sp = (l >> 4) ^ ((row >> 1) & 3);
      af[mi] = *(const bf16x8*)&a_lds[buf][row * 32 + sp * 8];
    }
#pragma unroll
    for (int ni = 0; ni < 4; ++ni) {
      int row = wn * 64 + ni * 16 + (l & 15);
      int sp = (l >> 4) ^ ((row >> 1) & 3);
      bf[ni] = *(const bf16x8*)&b_lds[buf][row * 32 + sp * 8];
    }
#pragma unroll
    for (int mi = 0; mi < 4; ++mi)
#pragma unroll
      for (int ni = 0; ni < 4; ++ni)
        acc[mi][ni] = MFMA16(af[mi], bf[ni], acc[mi][ni]);
    buf ^= 1;
  }

#pragma unroll
  for (int mi = 0; mi < 4; ++mi) {
    int rbase = bm * 128 + wm * 64 + mi * 16 + ((l >> 4) << 2);
#pragma unroll
    for (int ni = 0; ni < 4; ++ni) {
      int col = bn * 128 + wn * 64 + ni * 16 + (l & 15);
      f32x4 v = acc[mi][ni];
#pragma unroll
      for (int j = 0; j < 4; ++j)
        C[(size_t)(rbase + j) * N + col] = v[j];
    }
  }
}

// ---------- causal flash attention (swapped-QK^T, counted-vmcnt pipeline) ----------
// Q: bf16 [b,h,s,64] pre-scaled by 0.125/ln2; K: bf16 [b,h,s,64]; Vt: bf16 [b,h,dk,s];
// O: bf16 [b,s,h*64+dk]. LDS = 32KB (K/V double-buffered only; Q frags in regs)
// -> 4+ blocks/CU, all 1024 blocks co-resident. Raw s_barrier + s_waitcnt vmcnt(4)
// keeps prefetch in flight across barriers (no vmcnt(0) drain per tile).

__global__ __launch_bounds__(256, 4)
void attn_k(const u16* __restrict__ Q, const u16* __restrict__ K,
            const u16* __restrict__ V, u16* __restrict__ O) {
  const int S = 2048;
  __shared__ u16 k_lds[2][64 * 64];
  __shared__ u16 v_lds[2][64 * 64];       // [dk][kv]

  const int tid = threadIdx.x, l = tid & 63, w = tid >> 6;
  const int c = l & 15, h = l >> 4;

  // bijective XCD swizzle: XCD x gets bh in [8x, 8x+8)
  const int wg = blockIdx.x;                       // 1024
  const int idx = (wg & 7) * 128 + (wg >> 3);
  const int bh = idx >> 4, pairI = idx & 15;

  const u16* Kb = K + (size_t)bh * S * 64;
  const u16* Vb = V + (size_t)bh * 64 * S;
  const int b = bh >> 4, hd = bh & 15;
  const f32x4 fz = {0.f, 0.f, 0.f, 0.f};

  // loop-invariant bpermute lane addresses for PV A-frag assembly
  int bperm[4];
#pragma unroll
  for (int tt = 0; tt < 4; ++tt)
    bperm[tt] = ((((l & 16) << 1) | ((tt >> 1) << 4) | c) << 2);

  auto stageKV = [&](int bq, int kv0) {
#pragma unroll
    for (int half = 0; half < 2; ++half) {
      int t = half * 256 + tid;
      int row = t >> 3, slot = t & 7;
      int sp = slot ^ (row & 7);
      gl_lds16(Kb + (size_t)(kv0 + row) * 64 + sp * 8, &k_lds[bq][t * 8]);
      gl_lds16(Vb + (size_t)row * S + kv0 + sp * 8, &v_lds[bq][t * 8]);
    }
  };

#pragma unroll 1
  for (int ph = 0; ph < 2; ++ph) {
    const int qi = ph ? (31 - pairI) : pairI;
    const int q0 = qi * 64;
    const int nkv = qi + 1;
    const u16* Qb = Q + ((size_t)bh * S + q0) * 64;

    // Q fragments straight to registers (issued first so vmcnt(4) covers them)
    bf16x8 qf[2];
#pragma unroll
    for (int ks = 0; ks < 2; ++ks)
      qf[ks] = *(const bf16x8*)(Qb + (size_t)(w * 16 + c) * 64 + ks * 32 + h * 8);
    __builtin_amdgcn_sched_barrier(0);
    stageKV(0, 0);                      // 4 gl_lds16 for tile 0

    f32x4 oacc[4];
#pragma unroll
    for (int ni = 0; ni < 4; ++ni) oacc[ni] = fz;
    float m_run = -1e30f, l_run = 0.f;

    int buf = 0;
#pragma unroll 1
    for (int t = 0; t < nkv; ++t) {
      // issue next-tile prefetch, then wait leaving it in flight
      if (t + 1 < nkv) {
        stageKV(buf ^ 1, (t + 1) * 64);
        __builtin_amdgcn_sched_barrier(0);
        asm volatile("s_waitcnt vmcnt(4)" ::: "memory");
      } else {
        asm volatile("s_waitcnt vmcnt(0)" ::: "memory");
      }
      __builtin_amdgcn_sched_barrier(0);
      __builtin_amdgcn_s_barrier();      // all waves' tile-t staging complete
      __builtin_amdgcn_sched_barrier(0);

      // S^T = K * Q^T : C[kv, q]; lane: q = q0 + w*16 + c, kv = t*64 + kvb*16 + 4h + j
      f32x4 sc[4];
#pragma unroll
      for (int kvb = 0; kvb < 4; ++kvb) sc[kvb] = fz;
      __builtin_amdgcn_s_setprio(1);
#pragma unroll
      for (int ks = 0; ks < 2; ++ks)
#pragma unroll
        for (int kvb = 0; kvb < 4; ++kvb) {
          int row = kvb * 16 + c;
          int sp = (4 * ks + h) ^ (row & 7);
          bf16x8 kf = *(const bf16x8*)&k_lds[buf][row * 64 + sp * 8];
          sc[kvb] = MFMA16(kf, qf[ks], sc[kvb]);
        }
      __builtin_amdgcn_s_setprio(0);

      // causal mask (only diagonal tile)
      if (t == qi) {
        int qg = q0 + w * 16 + c;
#pragma unroll
        for (int kvb = 0; kvb < 4; ++kvb)
#pragma unroll
          for (int j = 0; j < 4; ++j) {
            int kvg = t * 64 + kvb * 16 + 4 * h + j;
            if (kvg > qg) sc[kvb][j] = -1e30f;
          }
      }

      // online softmax (exp2 domain; row is lane-local, 2-shfl full-row reduce)
      float mx = -1e30f;
#pragma unroll
      for (int kvb = 0; kvb < 4; ++kvb)
#pragma unroll
        for (int j = 0; j < 4; ++j) mx = fmaxf(mx, sc[kvb][j]);
      mx = fmaxf(mx, __shfl_xor(mx, 16));
      mx = fmaxf(mx, __shfl_xor(mx, 32));

      const bool norescale = __all(mx <= m_run);
      float mnew = norescale ? m_run : fmaxf(m_run, mx);
      float ps = 0.f;
#pragma unroll
      for (int kvb = 0; kvb < 4; ++kvb)
#pragma unroll
        for (int j = 0; j < 4; ++j) {
          float e = exp2f(sc[kvb][j] - mnew);
          sc[kvb][j] = e;
          ps += e;
        }
      ps += __shfl_xor(ps, 16);
      ps += __shfl_xor(ps, 32);

      if (norescale) {
        l_run += ps;
      } else {
        float alpha = exp2f(m_run - mnew);
        l_run = l_run * alpha + ps;
        m_run = mnew;
        float aj[4];
#pragma unroll
        for (int j = 0; j < 4; ++j) aj[j] = __shfl(alpha, 20 * h + j);
#pragma unroll
        for (int ni = 0; ni < 4; ++ni)
#pragma unroll
          for (int j = 0; j < 4; ++j) oacc[ni][j] *= aj[j];
      }

      // pack P to bf16 pairs via hardware cvt_pk
      u32 pk[4][2];
#pragma unroll
      for (int kvb = 0; kvb < 4; ++kvb) {
        pk[kvb][0] = cvt_pk_bf16(sc[kvb][0], sc[kvb][1]);
        pk[kvb][1] = cvt_pk_bf16(sc[kvb][2], sc[kvb][3]);
      }

      // O += P * V : A-frag = P[q, kv] assembled via ds_bpermute (hoisted addrs)
#pragma unroll
      for (int ks = 0; ks < 2; ++ks) {
        union { u32 u[4]; bf16x8 v; } af;
#pragma unroll
        for (int tt = 0; tt < 4; ++tt) {
          u32 lo = (u32)__builtin_amdgcn_ds_bpermute(bperm[tt], (int)pk[2 * ks][tt & 1]);
          u32 hi = (u32)__builtin_amdgcn_ds_bpermute(bperm[tt], (int)pk[2 * ks + 1][tt & 1]);
          af.u[tt] = (l & 32) ? hi : lo;
        }
        __builtin_amdgcn_s_setprio(1);
#pragma unroll
        for (int ni = 0; ni < 4; ++ni) {
          int row = ni * 16 + c;
          int sp = (4 * ks + h) ^ (row & 7);
          bf16x8 vf = *(const bf16x8*)&v_lds[buf][row * 64 + sp * 8];
          oacc[ni] = MFMA16(af.v, vf, oacc[ni]);
        }
        __builtin_amdgcn_s_setprio(0);
      }

      __builtin_amdgcn_sched_barrier(0);
      __builtin_amdgcn_s_barrier();      // readers of lds[buf] done -> reusable
      __builtin_amdgcn_sched_barrier(0);
      buf ^= 1;
    }

    // epilogue: normalize and write bf16 [b, s, hd*64+dk]; oacc row = 4h+j
    float invl[4];
#pragma unroll
    for (int j = 0; j < 4; ++j)
      invl[j] = 1.f / __shfl(l_run, 20 * h + j);
#pragma unroll
    for (int ni = 0; ni < 4; ++ni)
#pragma unroll
      for (int j = 0; j < 4; ++j) {
        int srow = q0 + w * 16 + 4 * h + j;
        int dk = ni * 16 + c;
        O[((size_t)(b * 2048 + srow) << 10) + hd * 64 + dk] = f2bf(oacc[ni][j] * invl[j]);
      }
  }
}

// ---------- launch ----------

extern "C" void kernel_launch(void* const* d_in, const int* in_sizes, int n_in,
                              void* d_out, int out_size, void* d_ws, size_t ws_size,
                              hipStream_t stream) {
  (void)in_sizes; (void)n_in; (void)out_size; (void)ws_size;
  const float* x  = (const float*)d_in[0];
  const int* pos  = (const int*)d_in[1];
  const float* Wq = (const float*)d_in[2];
  const float* Wk = (const float*)d_in[3];
  const float* Wv = (const float*)d_in[4];
  const float* Wo = (const float*)d_in[5];
  float* out = (float*)d_out;

  const int S = 2048, D = 1024;
  const size_t M = (size_t)4 * S;          // 8192

  char* ws = (char*)d_ws;
  size_t off = 0;
  auto alloc = [&](size_t bytes) {
    void* p = ws + off;
    off += (bytes + 255) & ~(size_t)255;
    return p;
  };
  u16* xb   = (u16*)alloc(M * D * 2);
  u16* wqb  = (u16*)alloc((size_t)D * D * 2);   // wqb|wkb|wvb contiguous (2MB each)
  u16* wkb  = (u16*)alloc((size_t)D * D * 2);
  u16* wvb  = (u16*)alloc((size_t)D * D * 2);
  u16* wob  = (u16*)alloc((size_t)D * D * 2);
  u16* Qr   = (u16*)alloc(M * D * 2);
  u16* Kr   = (u16*)alloc(M * D * 2);
  u16* Vt   = (u16*)alloc(M * D * 2);
  u16* Ob   = (u16*)alloc(M * D * 2);
  float2* csT = (float2*)alloc((size_t)S * 32 * 8);

  cast_all_k<<<12288, 256, 0, stream>>>(x, Wq, Wk, Wv, Wo, xb, wqb, wkb, wvb, wob);
  rope_table_k<<<(S * 32) / 256, 256, 0, stream>>>(pos, csT);

  // Q scale: 1/sqrt(64) folded with 1/ln2 so attention logits are in exp2 domain
  const float QSCALE = 0.125f * 1.4426950408889634f;

  gemm_qkv<<<dim3(24, (unsigned)(M / 128)), 256, 0, stream>>>(
      xb, wqb, csT, Qr, Kr, Vt, QSCALE);
  attn_k<<<1024, 256, 0, stream>>>(Qr, Kr, Vt, Ob);
  gemm_bt<<<dim3(8, (unsigned)(M / 128)), 256, 0, stream>>>(Ob, wob, out, (int)M, D, D);
}